// Round 4
// baseline (615.790 us; speedup 1.0000x reference)
//
#include <hip/hip_runtime.h>
#include <cstddef>
#include <cstdint>

#define S_TOK 8192
#define DDIM  2048
#define NEXP  64
#define CAPTY 128
#define KC    64
#define TPB   64                       // tokens per chunk
#define NBLK  (S_TOK / TPB)            // 128 chunks
#define SPLITK 8
#define KPER  (DDIM / SPLITK)          // 256
#define SEC   ((size_t)S_TOK * NEXP * CAPTY)   // 67,108,864
#define NOUT  (1 + 2 * SEC)                    // 134,217,729 floats
#define F4_FILLONLY 24576                      // float4 per fill-only block (1024 blocks)
#define F4_GEMM     8192                       // float4 per gemm block (1024 blocks)

typedef float f32x4 __attribute__((ext_vector_type(4)));   // native vector: OK for
                                                           // __builtin_nontemporal_store

// ---------------------------------------------------------------------------
// Kernel 1: fused [zero-fill of out] + [split-K fp32 GEMM].
//  2048 blocks, parity-interleaved so each CU holds ~2 fill + ~2 GEMM blocks:
//   even blocks: stream 24576 nontemporal float4 zeros (3/4 of the fill).
//   odd  blocks: unchanged split-K GEMM (g = b>>1), then 8192 float4 zeros.
//  GEMM compute/LDS work hides under the fill's write bandwidth; previously
//  memset (85 us) and GEMM ran back-to-back on the stream.
//  NT stores keep wg/x resident in L2 while 537 MB streams past.
// ---------------------------------------------------------------------------
__global__ __launch_bounds__(256)
void fill_gemm_kernel(const float* __restrict__ x, const float* __restrict__ wg,
                      float* __restrict__ part, float* __restrict__ out)
{
    __shared__ float xs[TPB][72];       // 18,432 B
    __shared__ float ws[KC][NEXP];      // 16,384 B  (34.8 KB total -> 4 blk/CU)

    const int tid = threadIdx.x;
    const int b   = blockIdx.x;
    f32x4* __restrict__ out4 = (f32x4*)out;
    const f32x4 z4 = {0.f, 0.f, 0.f, 0.f};

    if ((b & 1) == 0) {
        // ---- fill-only block f = b>>1 : contiguous f4 range, coalesced ----
        const int f = b >> 1;
        size_t base = (size_t)f * F4_FILLONLY + tid;
#pragma unroll 8
        for (int j = 0; j < F4_FILLONLY / 256; ++j)
            __builtin_nontemporal_store(z4, &out4[base + (size_t)j * 256]);
        if (b == 0 && tid == 0) out[NOUT - 1] = 0.0f;   // scalar tail element
        return;
    }

    // ---- GEMM block g = b>>1 (identical math to the previous kernel) ----
    const int g   = b >> 1;
    const int el  = tid & 15;           // experts 4*el..4*el+3
    const int tg  = tid >> 4;           // tokens  tg, tg+16, tg+32, tg+48
    const int kp  = g & (SPLITK - 1);
    const int tc  = g >> 3;
    const int t_base = tc * TPB;
    const int k_base = kp * KPER;

    float acc[4][4];                    // [token i][expert j]
#pragma unroll
    for (int i = 0; i < 4; ++i)
#pragma unroll
        for (int j = 0; j < 4; ++j) acc[i][j] = 0.0f;

    for (int kc0 = 0; kc0 < KPER; kc0 += KC) {
        const int kc = k_base + kc0;
        __syncthreads();
        // stage x: 16 consecutive lanes read 256 contiguous bytes of one row
#pragma unroll
        for (int m = 0; m < 4; ++m) {
            int idx = tid + 256 * m;        // 0..1023
            int t = idx >> 4;               // row 0..63
            int c = idx & 15;               // float4 col 0..15
            float4 v = *(const float4*)(x + (size_t)(t_base + t) * DDIM + kc + c * 4);
            *(float4*)&xs[t][c * 4] = v;    // aligned b128, ~2-way banks
        }
        // stage wg: scatter along k (L2-absorbed), conflict-free b32 LDS writes
#pragma unroll
        for (int m = 0; m < 4; ++m) {
            int idx = tid + 256 * m;
            int e = idx & 63;               // expert row
            int c = idx >> 6;               // float4 col 0..15
            float4 w = *(const float4*)(wg + (size_t)e * DDIM + kc + c * 4);
            ws[c * 4 + 0][e] = w.x;
            ws[c * 4 + 1][e] = w.y;
            ws[c * 4 + 2][e] = w.z;
            ws[c * 4 + 3][e] = w.w;
        }
        __syncthreads();

#pragma unroll
        for (int k4 = 0; k4 < KC; k4 += 4) {
            float4 xv[4], wv[4];
#pragma unroll
            for (int i = 0; i < 4; ++i)
                xv[i] = *(const float4*)&xs[tg + 16 * i][k4];   // broadcast rows
#pragma unroll
            for (int j = 0; j < 4; ++j)
                wv[j] = *(const float4*)&ws[k4 + j][el * 4];    // 2-way banks
#pragma unroll
            for (int i = 0; i < 4; ++i) {
                acc[i][0] += xv[i].x * wv[0].x; acc[i][1] += xv[i].x * wv[0].y;
                acc[i][2] += xv[i].x * wv[0].z; acc[i][3] += xv[i].x * wv[0].w;
                acc[i][0] += xv[i].y * wv[1].x; acc[i][1] += xv[i].y * wv[1].y;
                acc[i][2] += xv[i].y * wv[1].z; acc[i][3] += xv[i].y * wv[1].w;
                acc[i][0] += xv[i].z * wv[2].x; acc[i][1] += xv[i].z * wv[2].y;
                acc[i][2] += xv[i].z * wv[2].z; acc[i][3] += xv[i].z * wv[2].w;
                acc[i][0] += xv[i].w * wv[3].x; acc[i][1] += xv[i].w * wv[3].y;
                acc[i][2] += xv[i].w * wv[3].z; acc[i][3] += xv[i].w * wv[3].w;
            }
        }
    }

#pragma unroll
    for (int i = 0; i < 4; ++i) {
        int t = tg + 16 * i;
        float4 v = make_float4(acc[i][0], acc[i][1], acc[i][2], acc[i][3]);
        *(float4*)(part + ((size_t)kp * S_TOK + t_base + t) * NEXP + el * 4) = v;
    }

    // ---- this block's fill share (1/4 of total, after GEMM) ----
    size_t base = (size_t)1024 * F4_FILLONLY + (size_t)g * F4_GEMM + tid;
#pragma unroll 8
    for (int j = 0; j < F4_GEMM / 256; ++j)
        __builtin_nontemporal_store(z4, &out4[base + (size_t)j * 256]);
}

// ---------------------------------------------------------------------------
// Kernel 2: reduce split-K partials + softmax/argmax/rank/hist per chunk.
// ---------------------------------------------------------------------------
__global__ __launch_bounds__(256)
void softmax_kernel(const float* __restrict__ part,
                    float* __restrict__ gate_s, int* __restrict__ expert,
                    int* __restrict__ rank, int* __restrict__ hist,
                    float* __restrict__ partial_g)
{
    __shared__ float probs[TPB][NEXP + 1];
    __shared__ int   sexp[TPB];

    const int tid = threadIdx.x;
    const int t_base = blockIdx.x * TPB;
    const int t = tid >> 2, q = tid & 3;    // 4 threads per token
    const int tok = t_base + t;

#pragma unroll
    for (int jj = 0; jj < 4; ++jj) {
        float4 a = make_float4(0.f, 0.f, 0.f, 0.f);
#pragma unroll
        for (int kpp = 0; kpp < SPLITK; ++kpp) {
            float4 v = *(const float4*)(part + ((size_t)kpp * S_TOK + tok) * NEXP + q * 16 + jj * 4);
            a.x += v.x; a.y += v.y; a.z += v.z; a.w += v.w;
        }
        probs[t][q * 16 + jj * 4 + 0] = a.x;
        probs[t][q * 16 + jj * 4 + 1] = a.y;
        probs[t][q * 16 + jj * 4 + 2] = a.z;
        probs[t][q * 16 + jj * 4 + 3] = a.w;
    }
    __syncthreads();

    if (tid < TPB) {                    // one thread per token
        const int t2 = tid, tok2 = t_base + t2;
        float m = -1e30f; int am = 0;
        for (int e = 0; e < NEXP; ++e) {
            float v = probs[t2][e];
            if (v > m) { m = v; am = e; }       // strict > = np.argmax
        }
        float s = 0.0f;
        for (int e = 0; e < NEXP; ++e) s += __expf(probs[t2][e] - m);
        float rcp = 1.0f / s;                   // top-1 gate value
        for (int e = 0; e < NEXP; ++e)
            probs[t2][e] = __expf(probs[t2][e] - m) * rcp;
        sexp[t2] = am;
        gate_s[tok2] = rcp;
        expert[tok2] = am;
    }
    __syncthreads();

    if (tid < TPB) {                    // rank within chunk (token order)
        const int t2 = tid;
        const int am = sexp[t2];
        int r = 0;
        for (int u = 0; u < t2; ++u) r += (sexp[u] == am) ? 1 : 0;
        rank[t_base + t2] = r;
    } else if (tid < 2 * TPB) {         // per-expert histogram + gate sums
        const int e = tid - TPB;
        float pg = 0.0f; int cnt = 0;
        for (int u = 0; u < TPB; ++u) {
            pg  += probs[u][e];
            cnt += (sexp[u] == e) ? 1 : 0;
        }
        partial_g[blockIdx.x * NEXP + e] = pg;
        hist[blockIdx.x * NEXP + e]      = cnt;
    }
}

// ---------------------------------------------------------------------------
// Kernel 3: per-expert exclusive scan over 128 chunks + l_aux -> ws
// ---------------------------------------------------------------------------
__global__ __launch_bounds__(64)
void scan_kernel(const int* __restrict__ hist, const float* __restrict__ partial_g,
                 int* __restrict__ chunk_base, float* __restrict__ l_aux_ws)
{
    int e = threadIdx.x;   // 0..63, one wave
    int base = 0;
    float sg = 0.0f;
    for (int c = 0; c < NBLK; ++c) {
        chunk_base[c * NEXP + e] = base;
        base += hist[c * NEXP + e];
        sg   += partial_g[c * NEXP + e];
    }
    float v = sg * (float)base;            // sum_gates[e] * pre-drop count[e]
#pragma unroll
    for (int off = 32; off > 0; off >>= 1) v += __shfl_down(v, off);
    if (e == 0)
        l_aux_ws[0] = v * (64.0f / (8192.0f * 8192.0f));   // l_aux
}

// ---------------------------------------------------------------------------
// Kernel 4: scatter surviving tokens + l_aux into the zeroed output
// ---------------------------------------------------------------------------
__global__ __launch_bounds__(256)
void scatter_kernel(const float* __restrict__ gate_s, const int* __restrict__ expert,
                    const int* __restrict__ rank, const int* __restrict__ chunk_base,
                    const float* __restrict__ l_aux_ws, float* __restrict__ out)
{
    int s = blockIdx.x * 256 + threadIdx.x;
    if (s == 0) out[0] = l_aux_ws[0];
    if (s >= S_TOK) return;
    int e   = expert[s];
    int loc = chunk_base[(s >> 6) * NEXP + e] + rank[s];
    if (loc < CAPTY) {
        size_t idx = 1 + (size_t)s * (NEXP * CAPTY) + (size_t)e * CAPTY + loc;
        out[idx]       = gate_s[s];     // combine1_sec
        out[idx + SEC] = 1.0f;          // dispatch_mask
    }
}

extern "C" void kernel_launch(void* const* d_in, const int* in_sizes, int n_in,
                              void* d_out, int out_size, void* d_ws, size_t ws_size,
                              hipStream_t stream)
{
    const float* x  = (const float*)d_in[0];
    const float* wg = (const float*)d_in[1];
    float* out = (float*)d_out;
    char* ws = (char*)d_ws;

    float* part      = (float*)(ws + 0);                       // 16 MB
    size_t off = (size_t)SPLITK * S_TOK * NEXP * sizeof(float);
    float* gate_s    = (float*)(ws + off);          off += 32768;
    int*   expert    = (int*)  (ws + off);          off += 32768;
    int*   rank      = (int*)  (ws + off);          off += 32768;
    int*   hist      = (int*)  (ws + off);          off += 32768;
    float* partial_g = (float*)(ws + off);          off += 32768;
    int*   chunk_b   = (int*)  (ws + off);          off += 32768;
    float* l_aux_ws  = (float*)(ws + off);

    // Rounds 0-2 established: out_size is an ELEMENT count; the 2 GiB
    // fillBufferAligned dispatches in rocprof are the harness's own poison
    // fill of the full output allocation, not ours. Our 537 MB memset and
    // the GEMM were the two large serial pieces we control -> fused below
    // (zero-fill hides GEMM compute under write BW). No hipMemsetAsync.
    fill_gemm_kernel<<<2048, 256, 0, stream>>>(x, wg, part, out);
    softmax_kernel<<<NBLK, 256, 0, stream>>>(part, gate_s, expert, rank, hist, partial_g);
    scan_kernel<<<1, 64, 0, stream>>>(hist, partial_g, chunk_b, l_aux_ws);
    scatter_kernel<<<(S_TOK + 255) / 256, 256, 0, stream>>>(gate_s, expert, rank,
                                                            chunk_b, l_aux_ws, out);
}

// Round 5
// 600.540 us; speedup vs baseline: 1.0254x; 1.0254x over previous
//
#include <hip/hip_runtime.h>
#include <cstddef>
#include <cstdint>

#define S_TOK 8192
#define DDIM  2048
#define NEXP  64
#define CAPTY 128
#define KC    64
#define TPB   64                       // tokens per chunk
#define NBLK  (S_TOK / TPB)            // 128 chunks
#define SPLITK 8
#define KPER  (DDIM / SPLITK)          // 256
#define SEC   ((size_t)S_TOK * NEXP * CAPTY)   // 67,108,864
#define NOUT  ((size_t)1 + 2 * SEC)            // 134,217,729 floats

// ---------------------------------------------------------------------------
// Kernel 1: split-K fp32 GEMM, 8x8 register blocking.
//  64-thread blocks (1 wave), 1024 blocks = 128 token-chunks x SPLITK 8
//  = exactly 4 blocks/CU (LDS 34.8KB -> 4 fit), 1 wave/SIMD.
//  Thread (el8=tid&7, tg=tid>>3): tokens tg+8i (i=0..7), experts el8*8..+7.
//  Per k-quad: 16 ds_read_b128 per 256 FMAs (FMA-bound; old 4x4 was 8 per 64,
//  LDS-issue-bound at ~41us/CU aggregate; this is ~20us floor).
//  Accumulation order per output is IDENTICAL to the previous kernel
//  (k ascending within chunk, chunks ascending, same split-K mapping) so the
//  result is bit-identical (absmax stays 0.0).
// ---------------------------------------------------------------------------
__global__ __launch_bounds__(64)
void gate_gemm_kernel(const float* __restrict__ x, const float* __restrict__ wg,
                      float* __restrict__ part)
{
    __shared__ float xs[TPB][72];       // 18,432 B (row pad 72: 16B-aligned)
    __shared__ float ws[KC][NEXP];      // 16,384 B  (34.8 KB total -> 4 blk/CU)

    const int tid = threadIdx.x;        // 0..63
    const int el8 = tid & 7;            // experts el8*8 .. el8*8+7
    const int tg  = tid >> 3;           // tokens tg + 8*i
    const int kp  = blockIdx.x & (SPLITK - 1);
    const int tc  = blockIdx.x >> 3;
    const int t_base = tc * TPB;
    const int k_base = kp * KPER;

    float acc[8][8];
#pragma unroll
    for (int i = 0; i < 8; ++i)
#pragma unroll
        for (int j = 0; j < 8; ++j) acc[i][j] = 0.0f;

    for (int kc0 = 0; kc0 < KPER; kc0 += KC) {
        const int kc = k_base + kc0;
        __syncthreads();
        // stage x: 1024 float4 (64 rows x 16 cols); 16 consecutive lanes read
        // 256 contiguous bytes of one row -> coalesced.
#pragma unroll
        for (int m = 0; m < 16; ++m) {
            int idx = tid + 64 * m;         // 0..1023
            int t = idx >> 4;               // row 0..63
            int c = idx & 15;               // float4 col 0..15
            float4 v = *(const float4*)(x + (size_t)(t_base + t) * DDIM + kc + c * 4);
            *(float4*)&xs[t][c * 4] = v;    // aligned b128, 2-way banks (free)
        }
        // stage wg: scatter along k (wg slice is L2-hot), conflict-free b32 writes
#pragma unroll
        for (int m = 0; m < 16; ++m) {
            int idx = tid + 64 * m;
            int e = idx & 63;               // expert row
            int c = idx >> 6;               // float4 col 0..15
            float4 w = *(const float4*)(wg + (size_t)e * DDIM + kc + c * 4);
            ws[c * 4 + 0][e] = w.x;
            ws[c * 4 + 1][e] = w.y;
            ws[c * 4 + 2][e] = w.z;
            ws[c * 4 + 3][e] = w.w;
        }
        __syncthreads();

        // k-quad component step: w-row reads are 2-way bank (free) +
        // broadcast across tg; xv rows are broadcast across el8.
#define KSTEP(COMP)                                                          \
        {                                                                    \
            float4 w0 = *(const float4*)&ws[kk][el8 * 8];                    \
            float4 w1 = *(const float4*)&ws[kk][el8 * 8 + 4];                \
            ++kk;                                                            \
            _Pragma("unroll")                                                \
            for (int i = 0; i < 8; ++i) {                                    \
                float xc = xv[i].COMP;                                       \
                acc[i][0] += xc * w0.x; acc[i][1] += xc * w0.y;              \
                acc[i][2] += xc * w0.z; acc[i][3] += xc * w0.w;              \
                acc[i][4] += xc * w1.x; acc[i][5] += xc * w1.y;              \
                acc[i][6] += xc * w1.z; acc[i][7] += xc * w1.w;              \
            }                                                                \
        }

#pragma unroll 2
        for (int k4 = 0; k4 < KC; k4 += 4) {
            float4 xv[8];
#pragma unroll
            for (int i = 0; i < 8; ++i)
                xv[i] = *(const float4*)&xs[tg + 8 * i][k4];
            int kk = k4;
            KSTEP(x) KSTEP(y) KSTEP(z) KSTEP(w)
        }
#undef KSTEP
    }

#pragma unroll
    for (int i = 0; i < 8; ++i) {
        int t = tg + 8 * i;
        float* p = part + ((size_t)kp * S_TOK + t_base + t) * NEXP + el8 * 8;
        *(float4*)(p + 0) = make_float4(acc[i][0], acc[i][1], acc[i][2], acc[i][3]);
        *(float4*)(p + 4) = make_float4(acc[i][4], acc[i][5], acc[i][6], acc[i][7]);
    }
}

// ---------------------------------------------------------------------------
// Kernel 2: reduce split-K partials + softmax/argmax/rank/hist per chunk.
// 128 blocks x 256 threads (4 threads per token for the reduction).
// ---------------------------------------------------------------------------
__global__ __launch_bounds__(256)
void softmax_kernel(const float* __restrict__ part,
                    float* __restrict__ gate_s, int* __restrict__ expert,
                    int* __restrict__ rank, int* __restrict__ hist,
                    float* __restrict__ partial_g)
{
    __shared__ float probs[TPB][NEXP + 1];
    __shared__ int   sexp[TPB];

    const int tid = threadIdx.x;
    const int t_base = blockIdx.x * TPB;
    const int t = tid >> 2, q = tid & 3;    // 4 threads per token
    const int tok = t_base + t;

#pragma unroll
    for (int jj = 0; jj < 4; ++jj) {
        float4 a = make_float4(0.f, 0.f, 0.f, 0.f);
#pragma unroll
        for (int kpp = 0; kpp < SPLITK; ++kpp) {
            float4 v = *(const float4*)(part + ((size_t)kpp * S_TOK + tok) * NEXP + q * 16 + jj * 4);
            a.x += v.x; a.y += v.y; a.z += v.z; a.w += v.w;
        }
        probs[t][q * 16 + jj * 4 + 0] = a.x;
        probs[t][q * 16 + jj * 4 + 1] = a.y;
        probs[t][q * 16 + jj * 4 + 2] = a.z;
        probs[t][q * 16 + jj * 4 + 3] = a.w;
    }
    __syncthreads();

    if (tid < TPB) {                    // one thread per token
        const int t2 = tid, tok2 = t_base + t2;
        float m = -1e30f; int am = 0;
        for (int e = 0; e < NEXP; ++e) {
            float v = probs[t2][e];
            if (v > m) { m = v; am = e; }       // strict > = np.argmax
        }
        float s = 0.0f;
        for (int e = 0; e < NEXP; ++e) s += __expf(probs[t2][e] - m);
        float rcp = 1.0f / s;                   // top-1 gate value
        for (int e = 0; e < NEXP; ++e)
            probs[t2][e] = __expf(probs[t2][e] - m) * rcp;
        sexp[t2] = am;
        gate_s[tok2] = rcp;
        expert[tok2] = am;
    }
    __syncthreads();

    if (tid < TPB) {                    // rank within chunk (token order)
        const int t2 = tid;
        const int am = sexp[t2];
        int r = 0;
        for (int u = 0; u < t2; ++u) r += (sexp[u] == am) ? 1 : 0;
        rank[t_base + t2] = r;
    } else if (tid < 2 * TPB) {         // per-expert histogram + gate sums
        const int e = tid - TPB;
        float pg = 0.0f; int cnt = 0;
        for (int u = 0; u < TPB; ++u) {
            pg  += probs[u][e];
            cnt += (sexp[u] == e) ? 1 : 0;
        }
        partial_g[blockIdx.x * NEXP + e] = pg;
        hist[blockIdx.x * NEXP + e]      = cnt;
    }
}

// ---------------------------------------------------------------------------
// Kernel 3: per-expert exclusive scan over 128 chunks + l_aux -> ws
// ---------------------------------------------------------------------------
__global__ __launch_bounds__(64)
void scan_kernel(const int* __restrict__ hist, const float* __restrict__ partial_g,
                 int* __restrict__ chunk_base, float* __restrict__ l_aux_ws)
{
    int e = threadIdx.x;   // 0..63, one wave
    int base = 0;
    float sg = 0.0f;
    for (int c = 0; c < NBLK; ++c) {
        chunk_base[c * NEXP + e] = base;
        base += hist[c * NEXP + e];
        sg   += partial_g[c * NEXP + e];
    }
    float v = sg * (float)base;            // sum_gates[e] * pre-drop count[e]
#pragma unroll
    for (int off = 32; off > 0; off >>= 1) v += __shfl_down(v, off);
    if (e == 0)
        l_aux_ws[0] = v * (64.0f / (8192.0f * 8192.0f));   // l_aux
}

// ---------------------------------------------------------------------------
// Kernel 4: scatter surviving tokens + l_aux into the zeroed output
// ---------------------------------------------------------------------------
__global__ __launch_bounds__(256)
void scatter_kernel(const float* __restrict__ gate_s, const int* __restrict__ expert,
                    const int* __restrict__ rank, const int* __restrict__ chunk_base,
                    const float* __restrict__ l_aux_ws, float* __restrict__ out)
{
    int s = blockIdx.x * 256 + threadIdx.x;
    if (s == 0) out[0] = l_aux_ws[0];
    if (s >= S_TOK) return;
    int e   = expert[s];
    int loc = chunk_base[(s >> 6) * NEXP + e] + rank[s];
    if (loc < CAPTY) {
        size_t idx = 1 + (size_t)s * (NEXP * CAPTY) + (size_t)e * CAPTY + loc;
        out[idx]       = gate_s[s];     // combine1_sec
        out[idx + SEC] = 1.0f;          // dispatch_mask
    }
}

extern "C" void kernel_launch(void* const* d_in, const int* in_sizes, int n_in,
                              void* d_out, int out_size, void* d_ws, size_t ws_size,
                              hipStream_t stream)
{
    const float* x  = (const float*)d_in[0];
    const float* wg = (const float*)d_in[1];
    float* out = (float*)d_out;
    char* ws = (char*)d_ws;

    float* part      = (float*)(ws + 0);                       // 16 MB
    size_t off = (size_t)SPLITK * S_TOK * NEXP * sizeof(float);
    float* gate_s    = (float*)(ws + off);          off += 32768;
    int*   expert    = (int*)  (ws + off);          off += 32768;
    int*   rank      = (int*)  (ws + off);          off += 32768;
    int*   hist      = (int*)  (ws + off);          off += 32768;
    float* partial_g = (float*)(ws + off);          off += 32768;
    int*   chunk_b   = (int*)  (ws + off);          off += 32768;
    float* l_aux_ws  = (float*)(ws + off);

    // Round-4 lesson: fusing the zero-fill into the GEMM REGRESSED (+22us) --
    // keep the rocclr fill path (measured 6.3-6.4 TB/s) and serial structure
    // from round 2 (best: 593.8us). The 2 GiB fillBufferAligned dispatches in
    // rocprof are the harness's poison fill, not ours.
    gate_gemm_kernel<<<NBLK * SPLITK, 64, 0, stream>>>(x, wg, part);
    softmax_kernel<<<NBLK, 256, 0, stream>>>(part, gate_s, expert, rank, hist, partial_g);
    scan_kernel<<<1, 64, 0, stream>>>(hist, partial_g, chunk_b, l_aux_ws);
    hipMemsetAsync(d_out, 0, NOUT * sizeof(float), stream);
    scatter_kernel<<<(S_TOK + 255) / 256, 256, 0, stream>>>(gate_s, expert, rank,
                                                            chunk_b, l_aux_ws, out);
}